// Round 1
// baseline (154.048 us; speedup 1.0000x reference)
//
#include <hip/hip_runtime.h>

// Problem constants (fixed by setup_inputs)
constexpr int B     = 512;
constexpr int H_IN  = 128;
constexpr int W_INw = 64;    // W_in
constexpr int H_OUT = 256;
constexpr int W_OUT = 64;
constexpr int K     = 4;
constexpr int D     = W_INw * K;  // 256
constexpr int BT    = 64;         // batch tile per block

// out[b,h,o] = sum_d gathered[b,h,d] * W[h,o,d] + bias[h,o]
// gathered[b,h, k*64+w] = x[b, mask[h,k], w]
__global__ __launch_bounds__(256) void sparse_linear_f32(
    const float* __restrict__ x,      // [B, H_IN, W_INw]
    const int*   __restrict__ mask,   // [H_OUT, K]
    const float* __restrict__ W,      // [H_OUT, W_OUT, D]
    const float* __restrict__ bias,   // [H_OUT, W_OUT]
    float*       __restrict__ out)    // [B, H_OUT, W_OUT]
{
    const int h   = blockIdx.x;       // 0..H_OUT-1
    const int b0  = blockIdx.y * BT;  // batch tile start
    const int tid = threadIdx.x;      // 0..255
    const int tx  = tid & 15;         // output-col group (4 cols each)
    const int ty  = tid >> 4;         // batch-row group (4 rows each)

    // As stride 68: b128 reads 16B-aligned, 2-way bank alias (free).
    // Ws stride 65: scalar broadcast reads hit 16 distinct banks (conflict-free).
    __shared__ float As[BT][68];
    __shared__ float Ws[W_OUT][65];

    float acc[4][4] = {};

    for (int kc = 0; kc < K; ++kc) {
        const int row = mask[h * K + kc];

        __syncthreads();  // protect previous chunk's LDS reads

        // Stage A chunk: 64 batch rows x 64 w  (coalesced float4 per thread x4)
        // Stage W chunk: 64 out cols  x 64 w
        #pragma unroll
        for (int p = 0; p < 4; ++p) {
            const int v  = tid + p * 256;   // 0..1023
            const int r  = v >> 4;          // 0..63
            const int w4 = (v & 15) << 2;   // 0,4,...,60

            const float4 a = *(const float4*)(x + ((size_t)(b0 + r) * H_IN + row) * W_INw + w4);
            *(float4*)&As[r][w4] = a;       // stride 68 -> 16B aligned

            const float4 wv = *(const float4*)(W + ((size_t)h * W_OUT + r) * D + kc * W_INw + w4);
            Ws[r][w4 + 0] = wv.x;           // stride 65: scalar writes (unaligned for b128)
            Ws[r][w4 + 1] = wv.y;
            Ws[r][w4 + 2] = wv.z;
            Ws[r][w4 + 3] = wv.w;
        }
        __syncthreads();

        // Compute: each thread does rows 4*ty..+3, cols 4*tx..+3 over this 64-d chunk
        #pragma unroll
        for (int d = 0; d < W_INw; d += 4) {
            float av[4][4];
            #pragma unroll
            for (int i = 0; i < 4; ++i)
                *(float4*)av[i] = *(const float4*)&As[4 * ty + i][d];

            #pragma unroll
            for (int c = 0; c < 4; ++c) {
                float wv[4];
                #pragma unroll
                for (int j = 0; j < 4; ++j)
                    wv[j] = Ws[4 * tx + j][d + c];
                #pragma unroll
                for (int i = 0; i < 4; ++i)
                    #pragma unroll
                    for (int j = 0; j < 4; ++j)
                        acc[i][j] = fmaf(av[i][c], wv[j], acc[i][j]);
            }
        }
    }

    // Epilogue: bias + coalesced float4 stores
    float bb[4];
    *(float4*)bb = *(const float4*)(bias + h * W_OUT + 4 * tx);

    #pragma unroll
    for (int i = 0; i < 4; ++i) {
        const int b = b0 + 4 * ty + i;
        float4 o4;
        o4.x = acc[i][0] + bb[0];
        o4.y = acc[i][1] + bb[1];
        o4.z = acc[i][2] + bb[2];
        o4.w = acc[i][3] + bb[3];
        *(float4*)(out + ((size_t)b * H_OUT + h) * W_OUT + 4 * tx) = o4;
    }
}

extern "C" void kernel_launch(void* const* d_in, const int* in_sizes, int n_in,
                              void* d_out, int out_size, void* d_ws, size_t ws_size,
                              hipStream_t stream) {
    const float* x    = (const float*)d_in[0];
    const int*   mask = (const int*)d_in[1];
    const float* W    = (const float*)d_in[2];
    const float* bias = (const float*)d_in[3];
    float* out = (float*)d_out;

    dim3 grid(H_OUT, B / BT);  // 256 x 8
    dim3 block(256);
    sparse_linear_f32<<<grid, block, 0, stream>>>(x, mask, W, bias, out);
}

// Round 3
// 128.413 us; speedup vs baseline: 1.1996x; 1.1996x over previous
//
#include <hip/hip_runtime.h>

// Problem constants (fixed by setup_inputs)
constexpr int Bsz   = 512;
constexpr int H_IN  = 128;
constexpr int Wl    = 64;    // W_in
constexpr int H_OUT = 256;
constexpr int W_OUT = 64;
constexpr int KC    = 4;     // gather K
constexpr int D     = 256;   // Wl * KC
constexpr int BT    = 64;    // batch tile per block

typedef __bf16 bf16x8 __attribute__((ext_vector_type(8)));
typedef float  f32x16 __attribute__((ext_vector_type(16)));

// fp32 -> bf16, round-to-nearest-even (no NaN in this problem)
__device__ inline ushort f2bf(float f) {
    uint u = __float_as_uint(f);
    u = (u + 0x7FFFu + ((u >> 16) & 1u)) >> 16;
    return (ushort)u;
}

struct US8 { ushort s[8]; };

__device__ inline float4 pack8(float4 lo, float4 hi) {
    US8 r;
    r.s[0] = f2bf(lo.x); r.s[1] = f2bf(lo.y);
    r.s[2] = f2bf(lo.z); r.s[3] = f2bf(lo.w);
    r.s[4] = f2bf(hi.x); r.s[5] = f2bf(hi.y);
    r.s[6] = f2bf(hi.z); r.s[7] = f2bf(hi.w);
    return __builtin_bit_cast(float4, r);
}

// out[b,h,o] = sum_d x[b, mask[h, d/64], d%64] * W[h,o,d] + bias[h,o]
__global__ __launch_bounds__(256, 2) void sparse_linear_mfma(
    const float* __restrict__ x,      // [B, H_IN, Wl] fp32
    const int*   __restrict__ mask,   // [H_OUT, KC]
    const float* __restrict__ W,      // [H_OUT, W_OUT, D] fp32
    const float* __restrict__ bias,   // [H_OUT, W_OUT]
    float*       __restrict__ out)    // [B, H_OUT, W_OUT]
{
    const int h   = blockIdx.x;       // 0..255
    const int b0  = blockIdx.y * BT;  // batch tile start
    const int tid = threadIdx.x;

    // 64 rows x 32 slots of 16B (8 bf16) each, XOR-swizzled: slot ^= (row & 15).
    // Row stride 512B would otherwise put all 32 fragment-read lanes in one
    // bank group (16-way); swizzled, each bank serves exactly 8 distinct words
    // per b128 read = the conflict-free floor.
    __shared__ float4 Als[BT * 32];     // gathered x tile, bf16
    __shared__ float4 Wls[W_OUT * 32];  // W[h] tile, bf16

    // ---- Stage: thread (r, q) handles LDS row r, d-chunk q (one x row) ----
    const int r = tid >> 2;   // 0..63
    const int q = tid & 3;    // 0..3  (gather chunk)
    const int mrow = mask[h * KC + q];

    const float4* ax = (const float4*)(x + ((size_t)(b0 + r) * H_IN + mrow) * Wl);
    const float4* wx = (const float4*)(W + ((size_t)(h * W_OUT + r)) * D + q * Wl);

    #pragma unroll
    for (int j = 0; j < 8; ++j) {          // slot j covers d = q*64 + j*8 .. +7
        const int slot = (q * 8 + j) ^ (r & 15);
        Als[r * 32 + slot] = pack8(ax[2 * j], ax[2 * j + 1]);
        Wls[r * 32 + slot] = pack8(wx[2 * j], wx[2 * j + 1]);
    }
    __syncthreads();

    // ---- Compute: 4 waves, each a 32x32 output tile, K=256 in 16 steps ----
    const int lane = tid & 63;
    const int wid  = tid >> 6;
    const int wr   = (wid >> 1) * 32;   // batch-row half
    const int wc   = (wid & 1) * 32;    // out-col half
    const int rowl = lane & 31;
    const int hi   = lane >> 5;         // k-half within a k-step

    const int ra = wr + rowl;           // A row (batch)
    const int rb = wc + rowl;           // B row (out col; B[k][n] = W[n][k])

    f32x16 acc0 = {};
    f32x16 acc1 = {};

    #pragma unroll
    for (int ks = 0; ks < 16; ks += 2) {
        const int s0 = ks * 2 + hi;           // 16B slot = k/8
        const int s1 = (ks + 1) * 2 + hi;
        bf16x8 a0 = __builtin_bit_cast(bf16x8, Als[ra * 32 + (s0 ^ (ra & 15))]);
        bf16x8 b0 = __builtin_bit_cast(bf16x8, Wls[rb * 32 + (s0 ^ (rb & 15))]);
        bf16x8 a1 = __builtin_bit_cast(bf16x8, Als[ra * 32 + (s1 ^ (ra & 15))]);
        bf16x8 b1 = __builtin_bit_cast(bf16x8, Wls[rb * 32 + (s1 ^ (rb & 15))]);
        acc0 = __builtin_amdgcn_mfma_f32_32x32x16_bf16(a0, b0, acc0, 0, 0, 0);
        acc1 = __builtin_amdgcn_mfma_f32_32x32x16_bf16(a1, b1, acc1, 0, 0, 0);
    }

    // ---- Epilogue: C/D layout col=lane&31, row=(reg&3)+8*(reg>>2)+4*(lane>>5)
    const int   col = wc + rowl;
    const float bv  = bias[h * W_OUT + col];

    #pragma unroll
    for (int reg = 0; reg < 16; ++reg) {
        const int rl = (reg & 3) + 8 * (reg >> 2) + 4 * hi;
        const int b  = b0 + wr + rl;
        out[((size_t)b * H_OUT + h) * W_OUT + col] = acc0[reg] + acc1[reg] + bv;
    }
}

extern "C" void kernel_launch(void* const* d_in, const int* in_sizes, int n_in,
                              void* d_out, int out_size, void* d_ws, size_t ws_size,
                              hipStream_t stream) {
    const float* x    = (const float*)d_in[0];
    const int*   mask = (const int*)d_in[1];
    const float* W    = (const float*)d_in[2];
    const float* bias = (const float*)d_in[3];
    float* out = (float*)d_out;

    dim3 grid(H_OUT, Bsz / BT);  // (256, 8); h fastest => h%8 per XCD => W slice L2-fits
    dim3 block(256);
    sparse_linear_mfma<<<grid, block, 0, stream>>>(x, mask, W, bias, out);
}

// Round 5
// 111.460 us; speedup vs baseline: 1.3821x; 1.1521x over previous
//
#include <hip/hip_runtime.h>

// Problem constants (fixed by setup_inputs)
constexpr int H_OUT = 256;
constexpr int D     = 256;   // Wl * KC

typedef __bf16 bf16x8 __attribute__((ext_vector_type(8)));
typedef float  f32x16 __attribute__((ext_vector_type(16)));

// fp32 -> bf16, round-to-nearest-even
__device__ inline ushort f2bf(float f) {
    uint u = __float_as_uint(f);
    u = (u + 0x7FFFu + ((u >> 16) & 1u)) >> 16;
    return (ushort)u;
}

struct US8 { ushort s[8]; };

__device__ inline float4 pack8(float4 lo, float4 hi) {
    US8 r;
    r.s[0] = f2bf(lo.x); r.s[1] = f2bf(lo.y);
    r.s[2] = f2bf(lo.z); r.s[3] = f2bf(lo.w);
    r.s[4] = f2bf(hi.x); r.s[5] = f2bf(hi.y);
    r.s[6] = f2bf(hi.z); r.s[7] = f2bf(hi.w);
    return __builtin_bit_cast(float4, r);
}

// Block = (h, batch-half). Loops 4 batch-tiles of 64.
// W[h] B-fragments live in registers (loaded once); x tile double-buffered in LDS.
__global__ __launch_bounds__(256, 2) void sparse_linear_mfma2(
    const float* __restrict__ x,      // [512, 128, 64] fp32
    const int*   __restrict__ mask,   // [256, 4]
    const float* __restrict__ W,      // [256, 64, 256] fp32
    const float* __restrict__ bias,   // [256, 64]
    float*       __restrict__ out)    // [512, 256, 64]
{
    const int bx   = blockIdx.x;
    const int h    = bx & 255;        // bx%8 == h%8 -> per-XCD W slice = 2MB, L2-fits
    const int half = bx >> 8;         // 0/1: batches [0,256) / [256,512)
    const int tid  = threadIdx.x;
    const int lane = tid & 63, wid = tid >> 6;
    const int wr   = (wid >> 1) * 32;   // batch-row quarter (within 64-row tile)
    const int wc   = (wid & 1) * 32;    // out-col half
    const int rowl = lane & 31, hi = lane >> 5;

    // x tile: 64 rows x 32 slots of 16B (8 bf16), XOR-swizzled slot ^= (row&15).
    __shared__ float4 Als[2][64 * 32];  // 2 x 32 KB

    // ---- B fragments: this wave's 32 W[h] rows (out cols), all K, regs ----
    const int rb = wc + rowl;
    const float* wp = W + ((size_t)h * 64 + rb) * D + hi * 8;
    bf16x8 bfrag[16];
    #pragma unroll
    for (int ks = 0; ks < 16; ++ks) {
        float4 lo = *(const float4*)(wp + ks * 16);
        float4 h4 = *(const float4*)(wp + ks * 16 + 4);
        bfrag[ks] = __builtin_bit_cast(bf16x8, pack8(lo, h4));
    }

    const float bv = bias[h * 64 + wc + rowl];

    // ---- staging role: thread (r, q) handles LDS row r, gather chunk q ----
    const int r = tid >> 2, q = tid & 3;
    const int mrow = mask[h * 4 + q];
    const float* xrow0 = x + ((size_t)(half * 256 + r) * 128 + mrow) * 64;

    float4 xr[16];

    // prologue: stage tile 0
    {
        const float4* src = (const float4*)xrow0;
        #pragma unroll
        for (int j = 0; j < 16; ++j) xr[j] = src[j];
        #pragma unroll
        for (int j = 0; j < 8; ++j) {
            const int slot = (q * 8 + j) ^ (r & 15);
            Als[0][r * 32 + slot] = pack8(xr[2 * j], xr[2 * j + 1]);
        }
    }
    __syncthreads();

    const int ra = wr + rowl;

    #pragma unroll
    for (int bt = 0; bt < 4; ++bt) {
        // T14: issue next tile's global loads BEFORE compute (latency hides under MFMA)
        if (bt < 3) {
            const float4* src = (const float4*)(xrow0 + (size_t)(bt + 1) * 64 * 128 * 64);
            #pragma unroll
            for (int j = 0; j < 16; ++j) xr[j] = src[j];
        }

        // compute 64x64 tile from buf bt&1 (wave: 32x32, 2 acc chains for ILP)
        f32x16 acc0 = {}, acc1 = {};
        #pragma unroll
        for (int ks = 0; ks < 16; ks += 2) {
            bf16x8 a0 = __builtin_bit_cast(bf16x8,
                Als[bt & 1][ra * 32 + ((ks * 2 + hi) ^ (ra & 15))]);
            bf16x8 a1 = __builtin_bit_cast(bf16x8,
                Als[bt & 1][ra * 32 + (((ks + 1) * 2 + hi) ^ (ra & 15))]);
            acc0 = __builtin_amdgcn_mfma_f32_32x32x16_bf16(a0, bfrag[ks],     acc0, 0, 0, 0);
            acc1 = __builtin_amdgcn_mfma_f32_32x32x16_bf16(a1, bfrag[ks + 1], acc1, 0, 0, 0);
        }

        // epilogue: C/D layout col=lane&31, row=(reg&3)+8*(reg>>2)+4*hi
        #pragma unroll
        for (int reg = 0; reg < 16; ++reg) {
            const int rl = (reg & 3) + 8 * (reg >> 2) + 4 * hi;
            const size_t b = (size_t)half * 256 + bt * 64 + wr + rl;
            out[(b * H_OUT + h) * 64 + wc + rowl] = acc0[reg] + acc1[reg] + bv;
        }

        // write next tile into the other buffer (after this buf's reads)
        if (bt < 3) {
            #pragma unroll
            for (int j = 0; j < 8; ++j) {
                const int slot = (q * 8 + j) ^ (r & 15);
                Als[(bt + 1) & 1][r * 32 + slot] = pack8(xr[2 * j], xr[2 * j + 1]);
            }
        }
        __syncthreads();
    }
}

extern "C" void kernel_launch(void* const* d_in, const int* in_sizes, int n_in,
                              void* d_out, int out_size, void* d_ws, size_t ws_size,
                              hipStream_t stream) {
    const float* x    = (const float*)d_in[0];
    const int*   mask = (const int*)d_in[1];
    const float* W    = (const float*)d_in[2];
    const float* bias = (const float*)d_in[3];
    float* out = (float*)d_out;

    dim3 grid(512);   // (h 0..255) x (batch half 0..1); exactly 2 blocks/CU
    dim3 block(256);
    sparse_linear_mfma2<<<grid, block, 0, stream>>>(x, mask, W, bias, out);
}

// Round 6
// 97.520 us; speedup vs baseline: 1.5797x; 1.1429x over previous
//
#include <hip/hip_runtime.h>

// Problem constants (fixed by setup_inputs)
constexpr int H_OUT = 256;
constexpr int D     = 256;   // Wl * KC

typedef __bf16 bf16x8 __attribute__((ext_vector_type(8)));
typedef float  f32x16 __attribute__((ext_vector_type(16)));

// fp32 -> bf16, round-to-nearest-even
__device__ inline ushort f2bf(float f) {
    uint u = __float_as_uint(f);
    u = (u + 0x7FFFu + ((u >> 16) & 1u)) >> 16;
    return (ushort)u;
}

__device__ inline uint2 pack4(float4 v) {
    uint2 r;
    r.x = (uint)f2bf(v.x) | ((uint)f2bf(v.y) << 16);
    r.y = (uint)f2bf(v.z) | ((uint)f2bf(v.w) << 16);
    return r;
}

// Block = (h, batch-half), loops 4 batch-tiles of 64 rows.
// W[h] staged ONCE into LDS via fully-coalesced loads (1 KB contiguous per
// wave-instruction); x tiles staged coalesced (16 lanes per 256B gathered row)
// with T14 reg-prefetch. Fragments ds_read_b128 from XOR-swizzled LDS.
__global__ __launch_bounds__(256, 2) void sparse_linear_mfma3(
    const float* __restrict__ x,      // [512, 128, 64] fp32
    const int*   __restrict__ mask,   // [256, 4]
    const float* __restrict__ W,      // [256, 64, 256] fp32
    const float* __restrict__ bias,   // [256, 64]
    float*       __restrict__ out)    // [512, 256, 64]
{
    const int bx   = blockIdx.x;
    const int h    = bx & 255;        // bx%8 == h%8 -> same-XCD halves share W in L2
    const int half = bx >> 8;
    const int tid  = threadIdx.x;
    const int lane = tid & 63, wid = tid >> 6;
    const int wr   = (wid >> 1) * 32;   // batch-row quarter within tile
    const int wc   = (wid & 1) * 32;    // out-col half
    const int rowl = lane & 31, hi = lane >> 5;

    // Each region: 64 rows x 32 slots of 16B (8 bf16), swizzle slot ^= (row&15).
    __shared__ float4 Wls[64 * 32];   // 32 KB, resident whole kernel
    __shared__ float4 Xls[64 * 32];   // 32 KB, restaged per batch-tile

    // ---- Stage W[h] (64 rows x 256 k, fp32) -> bf16 LDS. Coalesced:
    // per iter each wave reads one row's 64 float4 = 1 KB contiguous.
    {
        const int wrow = tid >> 6;            // + p*4
        const int c    = tid & 63;            // float4 col within row (k = 4c)
        const float4* wsrc = (const float4*)(W + (size_t)h * 64 * D);
        #pragma unroll
        for (int p = 0; p < 16; ++p) {
            const int R = p * 4 + wrow;
            const float4 v = wsrc[R * 64 + c];
            const int s = c >> 1, hf = c & 1;
            *((uint2*)&Wls[R * 32 + (s ^ (R & 15))] + hf) = pack4(v);
        }
    }

    // ---- x staging roles: iter p covers gather chunk q=p>>2, rows (p&3)*16+(tid>>4),
    // 16 consecutive lanes read one 256B x row -> fully coalesced.
    const int xrr = tid >> 4;   // row-within-16-group
    const int xc  = tid & 15;   // float4 col within 256B row
    int mq[4];
    #pragma unroll
    for (int q = 0; q < 4; ++q) mq[q] = mask[h * 4 + q];

    float4 xr[16];

    // prologue: load + write x tile 0 (Xls untouched by W stage -> no barrier needed yet)
    #pragma unroll
    for (int p = 0; p < 16; ++p) {
        const int q  = p >> 2;
        const int rr = (p & 3) * 16 + xrr;
        xr[p] = *(const float4*)(x + ((size_t)(half * 256 + rr) * 128 + mq[q]) * 64 + xc * 4);
    }
    #pragma unroll
    for (int p = 0; p < 16; ++p) {
        const int q  = p >> 2;
        const int rr = (p & 3) * 16 + xrr;
        const int s  = q * 8 + (xc >> 1), hf = xc & 1;
        *((uint2*)&Xls[rr * 32 + (s ^ (rr & 15))] + hf) = pack4(xr[p]);
    }
    __syncthreads();

    const int   ra = wr + rowl;
    const int   rb = wc + rowl;
    const float bv = bias[h * 64 + wc + rowl];

    #pragma unroll
    for (int bt = 0; bt < 4; ++bt) {
        // T14: issue next tile's coalesced loads before compute
        if (bt < 3) {
            #pragma unroll
            for (int p = 0; p < 16; ++p) {
                const int q  = p >> 2;
                const int rr = (p & 3) * 16 + xrr;
                xr[p] = *(const float4*)(x + ((size_t)(half * 256 + (bt + 1) * 64 + rr) * 128
                                              + mq[q]) * 64 + xc * 4);
            }
        }

        // compute this 64x64 tile: wave does 32x32, 2 acc chains
        f32x16 acc0 = {}, acc1 = {};
        #pragma unroll
        for (int ks = 0; ks < 16; ks += 2) {
            bf16x8 a0 = __builtin_bit_cast(bf16x8, Xls[ra * 32 + ((ks * 2 + hi) ^ (ra & 15))]);
            bf16x8 b0 = __builtin_bit_cast(bf16x8, Wls[rb * 32 + ((ks * 2 + hi) ^ (rb & 15))]);
            bf16x8 a1 = __builtin_bit_cast(bf16x8, Xls[ra * 32 + (((ks + 1) * 2 + hi) ^ (ra & 15))]);
            bf16x8 b1 = __builtin_bit_cast(bf16x8, Wls[rb * 32 + (((ks + 1) * 2 + hi) ^ (rb & 15))]);
            acc0 = __builtin_amdgcn_mfma_f32_32x32x16_bf16(a0, b0, acc0, 0, 0, 0);
            acc1 = __builtin_amdgcn_mfma_f32_32x32x16_bf16(a1, b1, acc1, 0, 0, 0);
        }

        // epilogue: C/D layout col=lane&31, row=(reg&3)+8*(reg>>2)+4*hi
        #pragma unroll
        for (int reg = 0; reg < 16; ++reg) {
            const int rl = (reg & 3) + 8 * (reg >> 2) + 4 * hi;
            const size_t b = (size_t)half * 256 + bt * 64 + wr + rl;
            out[(b * H_OUT + h) * 64 + wc + rowl] = acc0[reg] + acc1[reg] + bv;
        }

        // single-buffer x: drain reads, write next tile, publish
        if (bt < 3) {
            __syncthreads();
            #pragma unroll
            for (int p = 0; p < 16; ++p) {
                const int q  = p >> 2;
                const int rr = (p & 3) * 16 + xrr;
                const int s  = q * 8 + (xc >> 1), hf = xc & 1;
                *((uint2*)&Xls[rr * 32 + (s ^ (rr & 15))] + hf) = pack4(xr[p]);
            }
            __syncthreads();
        }
    }
}

extern "C" void kernel_launch(void* const* d_in, const int* in_sizes, int n_in,
                              void* d_out, int out_size, void* d_ws, size_t ws_size,
                              hipStream_t stream) {
    const float* x    = (const float*)d_in[0];
    const int*   mask = (const int*)d_in[1];
    const float* W    = (const float*)d_in[2];
    const float* bias = (const float*)d_in[3];
    float* out = (float*)d_out;

    dim3 grid(512);   // (h 0..255) x (batch half 0..1); 2 blocks/CU
    dim3 block(256);
    sparse_linear_mfma3<<<grid, block, 0, stream>>>(x, mask, W, bias, out);
}